// Round 3
// baseline (231.498 us; speedup 1.0000x reference)
//
#include <hip/hip_runtime.h>
#include <math.h>

#define C_DIM 4
#define T_DIM 4096
#define D_DIM 1024
#define E_DIM 16
#define CAP   320
#define CT    (C_DIM * T_DIM)               // 16384 tokens
#define OUT_ONE ((size_t)CT * E_DIM * CAP)  // 83,886,080 elements per big output

#define ROUTER_BLOCKS (CT / 16)             // 1024
#define FILL_BLOCKS   1024
#define FILL_THREADS  ((size_t)FILL_BLOCKS * 256)

typedef float f32x4 __attribute__((ext_vector_type(4)));  // native vector: ok for nontemporal builtins

// ws layout (bytes):
//   0      : auxpart f32[64]   (atomic accumulation of softmax prob sums per (c,e)) - zeroed each call
//   256    : counts  i32[64]
//   512    : gate    f32[CT]
//   66048  : index   i32[CT]
//   131584 : rank    i32[CT]

// ---------------------------------------------------------------------------
// Fused kernel: blocks [0, ROUTER_BLOCKS) do the router math (jitter, 16 dots,
// softmax, argmax/gate, aux prob sums); blocks [ROUTER_BLOCKS, +FILL_BLOCKS)
// zero-fill the two big outputs with nontemporal float4 stores. All 2048
// blocks are co-resident (4 waves x 8 blocks/CU), so the 134MB read stream
// and 671MB write stream overlap inside one dispatch.
// ---------------------------------------------------------------------------
__global__ __launch_bounds__(256) void fused_router_fill_kernel(
    const float* __restrict__ in, const float* __restrict__ w,
    const float* __restrict__ noise, float* __restrict__ gate,
    int* __restrict__ index, float* __restrict__ auxpart,
    f32x4* __restrict__ out4)
{
    if (blockIdx.x >= ROUTER_BLOCKS) {
        // ---- zero-fill half ----
        const size_t n4 = (2 * OUT_ONE) / 4;              // 41,943,040 float4
        const int fb = blockIdx.x - ROUTER_BLOCKS;
        size_t i = (size_t)fb * 256 + threadIdx.x;
        const f32x4 z = {0.f, 0.f, 0.f, 0.f};
        #pragma unroll 4
        for (; i < n4; i += FILL_THREADS)
            __builtin_nontemporal_store(z, out4 + i);
        return;
    }

    // ---- router half ----
    __shared__ float psum[E_DIM];
    const int tid  = threadIdx.x;
    if (tid < E_DIM) psum[tid] = 0.0f;
    __syncthreads();

    const int wave = tid >> 6;
    const int lane = tid & 63;
    const int g0   = blockIdx.x * 16 + wave * 4;   // first of 4 tokens for this wave

    float acc[4][16];
    #pragma unroll
    for (int tk = 0; tk < 4; ++tk)
        #pragma unroll
        for (int e = 0; e < 16; ++e)
            acc[tk][e] = 0.0f;

    #pragma unroll
    for (int r = 0; r < 4; ++r) {
        const int d0 = r * 256 + lane * 4;
        float4 x[4];
        #pragma unroll
        for (int tk = 0; tk < 4; ++tk) {
            const float4 a = *(const float4*)(in    + (size_t)(g0 + tk) * D_DIM + d0);
            const float4 n = *(const float4*)(noise + (size_t)(g0 + tk) * D_DIM + d0);
            x[tk] = make_float4(a.x * n.x, a.y * n.y, a.z * n.z, a.w * n.w);
        }
        #pragma unroll
        for (int e = 0; e < 16; ++e) {
            const float4 wv = *(const float4*)(w + e * D_DIM + d0);
            #pragma unroll
            for (int tk = 0; tk < 4; ++tk) {
                acc[tk][e] += x[tk].x * wv.x + x[tk].y * wv.y
                            + x[tk].z * wv.z + x[tk].w * wv.w;
            }
        }
    }

    // reduce the 16 partial dots across the 64 lanes
    #pragma unroll
    for (int tk = 0; tk < 4; ++tk)
        #pragma unroll
        for (int e = 0; e < 16; ++e)
            #pragma unroll
            for (int off = 32; off; off >>= 1)
                acc[tk][e] += __shfl_down(acc[tk][e], off, 64);

    if (lane == 0) {
        #pragma unroll
        for (int tk = 0; tk < 4; ++tk) {
            const int g = g0 + tk;
            float m = -1e30f; int am = 0;
            #pragma unroll
            for (int e = 0; e < 16; ++e)
                if (acc[tk][e] > m) { m = acc[tk][e]; am = e; }
            float p[16]; float s = 0.0f;
            #pragma unroll
            for (int e = 0; e < 16; ++e) { p[e] = __expf(acc[tk][e] - m); s += p[e]; }
            const float inv = 1.0f / s;
            gate[g]  = inv;          // probs[argmax] = exp(0)/s
            index[g] = am;
            #pragma unroll
            for (int e = 0; e < 16; ++e)
                atomicAdd(&psum[e], p[e] * inv);
        }
    }
    __syncthreads();
    if (tid < 16) {
        const int c = blockIdx.x / 256;   // 256 router blocks per c
        atomicAdd(&auxpart[c * 16 + tid], psum[tid]);
    }
}

// ---------------------------------------------------------------------------
// Kernel B: per-c rank (cumsum of one-hot over T) + full per-expert counts.
// ---------------------------------------------------------------------------
__global__ __launch_bounds__(256) void rank_kernel(
    const int* __restrict__ index, int* __restrict__ rank, int* __restrict__ counts)
{
    __shared__ int hist[256 * 16];
    const int tid = threadIdx.x;
    const int c   = blockIdx.x;
    const int* idxrow = index + c * T_DIM;
    const int base = tid * 16;

    #pragma unroll
    for (int e = 0; e < 16; ++e) hist[base + e] = 0;
    __syncthreads();

    for (int j = 0; j < 16; ++j) {
        const int e = idxrow[base + j];
        hist[base + e] += 1;
    }
    __syncthreads();

    if (tid < 16) {
        int running = 0;
        for (int i = 0; i < 256; ++i) {
            const int v = hist[i * 16 + tid];
            hist[i * 16 + tid] = running;
            running += v;
        }
        counts[c * 16 + tid] = running;   // pre-truncation count (for density1)
    }
    __syncthreads();

    for (int j = 0; j < 16; ++j) {
        const int t = base + j;
        const int e = idxrow[t];
        const int r = hist[base + e] + 1;   // 1-based rank within expert e
        hist[base + e] = r;
        rank[c * T_DIM + t] = r;
    }
}

// ---------------------------------------------------------------------------
// Kernel C: scatter the <=64 nonzeros of dispatch/combine + aux loss.
// ---------------------------------------------------------------------------
__global__ __launch_bounds__(64) void finalize_kernel(
    const float* __restrict__ gate, const int* __restrict__ index,
    const int* __restrict__ rank, const int* __restrict__ counts,
    const float* __restrict__ auxpart, float* __restrict__ out)
{
    const int id = threadIdx.x;          // 0..63
    const int c  = id >> 4;
    const int tp = id & 15;
    const int cnt = counts[id];

    float term = ((float)cnt * (1.0f / T_DIM)) * (auxpart[id] * (1.0f / T_DIM));

    if (cnt > 0) {
        const int g  = c * T_DIM + tp;
        const int rk = rank[g];
        if (rk < CAP) {                       // kept within capacity
            const int idx = index[g];
            const int s   = (idx == 0) ? rk : 0;
            const size_t off = ((size_t)g * E_DIM + 0) * CAP + (size_t)s;
            out[off]            = 1.0f;       // dispatch
            out[OUT_ONE + off]  = gate[g];    // combine
        }
    }

    #pragma unroll
    for (int off = 32; off; off >>= 1)
        term += __shfl_down(term, off, 64);
    if (id == 0)
        out[2 * OUT_ONE] = 16.0f * term;      // aux_loss = E * sum(density1*proxy)
}

extern "C" void kernel_launch(void* const* d_in, const int* in_sizes, int n_in,
                              void* d_out, int out_size, void* d_ws, size_t ws_size,
                              hipStream_t stream) {
    const float* in    = (const float*)d_in[0];
    const float* w     = (const float*)d_in[1];
    const float* noise = (const float*)d_in[2];
    float* out = (float*)d_out;

    char* ws = (char*)d_ws;
    float* auxpart = (float*)(ws);
    int*   counts  = (int*)(ws + 256);
    float* gate    = (float*)(ws + 512);
    int*   index   = (int*)(ws + 512 + 65536);
    int*   rank    = (int*)(ws + 512 + 131072);

    (void)hipMemsetAsync(ws, 0, 256, stream);

    fused_router_fill_kernel<<<dim3(ROUTER_BLOCKS + FILL_BLOCKS), dim3(256), 0, stream>>>(
        in, w, noise, gate, index, auxpart, (f32x4*)out);
    rank_kernel<<<dim3(C_DIM), dim3(256), 0, stream>>>(index, rank, counts);
    finalize_kernel<<<dim3(1), dim3(64), 0, stream>>>(index ? gate : gate, index, rank, counts, auxpart, out);
}

// Round 4
// 188.123 us; speedup vs baseline: 1.2306x; 1.2306x over previous
//
#include <hip/hip_runtime.h>
#include <math.h>

#define C_DIM 4
#define T_DIM 4096
#define D_DIM 1024
#define E_DIM 16
#define CAP   320
#define CT    (C_DIM * T_DIM)               // 16384 tokens
#define OUT_ONE ((size_t)CT * E_DIM * CAP)  // 83,886,080 elements per big output

#define NBLOCKS 2048                         // 8 tokens per block
#define N4      ((2 * OUT_ONE) / 4)          // 41,943,040 float4 to zero
#define F4_PER_BLOCK (N4 / NBLOCKS)          // 20480 float4 per block (320KB)

// ws layout (bytes):
//   0      : auxpart f32[64]   (atomic softmax prob sums per (c,e)) - zeroed each call
//   256    : counts  i32[64]
//   512    : gate    f32[CT]
//   66048  : index   i32[CT]
//   131584 : rank    i32[CT]

// ---------------------------------------------------------------------------
// Uniform fused kernel: every block routes 8 tokens (2 per wave), then zero-
// fills its contiguous 20480-float4 slice of the output with PLAIN float4
// stores. Read stream (134MB) and write stream (671MB) interleave across the
// whole dispatch; register pressure is modest (acc[2][16]).
// ---------------------------------------------------------------------------
__global__ __launch_bounds__(256) void fused_router_fill_kernel(
    const float* __restrict__ in, const float* __restrict__ w,
    const float* __restrict__ noise, float* __restrict__ gate,
    int* __restrict__ index, float* __restrict__ auxpart,
    float4* __restrict__ out4)
{
    __shared__ float psum[E_DIM];
    const int tid  = threadIdx.x;
    if (tid < E_DIM) psum[tid] = 0.0f;
    __syncthreads();

    const int wave = tid >> 6;
    const int lane = tid & 63;
    const int g0   = blockIdx.x * 8 + wave * 2;   // 2 tokens per wave

    float acc[2][16];
    #pragma unroll
    for (int tk = 0; tk < 2; ++tk)
        #pragma unroll
        for (int e = 0; e < 16; ++e)
            acc[tk][e] = 0.0f;

    #pragma unroll
    for (int r = 0; r < 4; ++r) {
        const int d0 = r * 256 + lane * 4;
        float4 x[2];
        #pragma unroll
        for (int tk = 0; tk < 2; ++tk) {
            const float4 a = *(const float4*)(in    + (size_t)(g0 + tk) * D_DIM + d0);
            const float4 n = *(const float4*)(noise + (size_t)(g0 + tk) * D_DIM + d0);
            x[tk] = make_float4(a.x * n.x, a.y * n.y, a.z * n.z, a.w * n.w);
        }
        #pragma unroll
        for (int e = 0; e < 16; ++e) {
            const float4 wv = *(const float4*)(w + e * D_DIM + d0);
            #pragma unroll
            for (int tk = 0; tk < 2; ++tk) {
                acc[tk][e] += x[tk].x * wv.x + x[tk].y * wv.y
                            + x[tk].z * wv.z + x[tk].w * wv.w;
            }
        }
    }

    // reduce the 16 partial dots across the 64 lanes
    #pragma unroll
    for (int tk = 0; tk < 2; ++tk)
        #pragma unroll
        for (int e = 0; e < 16; ++e)
            #pragma unroll
            for (int off = 32; off; off >>= 1)
                acc[tk][e] += __shfl_down(acc[tk][e], off, 64);

    if (lane == 0) {
        #pragma unroll
        for (int tk = 0; tk < 2; ++tk) {
            const int g = g0 + tk;
            float m = -1e30f; int am = 0;
            #pragma unroll
            for (int e = 0; e < 16; ++e)
                if (acc[tk][e] > m) { m = acc[tk][e]; am = e; }
            float p[16]; float s = 0.0f;
            #pragma unroll
            for (int e = 0; e < 16; ++e) { p[e] = __expf(acc[tk][e] - m); s += p[e]; }
            const float inv = 1.0f / s;
            gate[g]  = inv;          // probs[argmax] = exp(0)/s
            index[g] = am;
            #pragma unroll
            for (int e = 0; e < 16; ++e)
                atomicAdd(&psum[e], p[e] * inv);
        }
    }
    __syncthreads();
    if (tid < 16) {
        const int c = blockIdx.x >> 9;    // 512 blocks per c
        atomicAdd(&auxpart[c * 16 + tid], psum[tid]);
    }

    // ---- zero-fill this block's contiguous slice (plain stores) ----
    const float4 z = make_float4(0.f, 0.f, 0.f, 0.f);
    float4* dst = out4 + (size_t)blockIdx.x * F4_PER_BLOCK;
    #pragma unroll 4
    for (int i = tid; i < F4_PER_BLOCK; i += 256)
        dst[i] = z;
}

// ---------------------------------------------------------------------------
// Kernel B: per-c rank (cumsum of one-hot over T) + full per-expert counts.
// ---------------------------------------------------------------------------
__global__ __launch_bounds__(256) void rank_kernel(
    const int* __restrict__ index, int* __restrict__ rank, int* __restrict__ counts)
{
    __shared__ int hist[256 * 16];
    const int tid = threadIdx.x;
    const int c   = blockIdx.x;
    const int* idxrow = index + c * T_DIM;
    const int base = tid * 16;

    #pragma unroll
    for (int e = 0; e < 16; ++e) hist[base + e] = 0;
    __syncthreads();

    for (int j = 0; j < 16; ++j) {
        const int e = idxrow[base + j];
        hist[base + e] += 1;
    }
    __syncthreads();

    if (tid < 16) {
        int running = 0;
        for (int i = 0; i < 256; ++i) {
            const int v = hist[i * 16 + tid];
            hist[i * 16 + tid] = running;
            running += v;
        }
        counts[c * 16 + tid] = running;   // pre-truncation count (for density1)
    }
    __syncthreads();

    for (int j = 0; j < 16; ++j) {
        const int t = base + j;
        const int e = idxrow[t];
        const int r = hist[base + e] + 1;   // 1-based rank within expert e
        hist[base + e] = r;
        rank[c * T_DIM + t] = r;
    }
}

// ---------------------------------------------------------------------------
// Kernel C: scatter the <=64 nonzeros of dispatch/combine + aux loss.
// ---------------------------------------------------------------------------
__global__ __launch_bounds__(64) void finalize_kernel(
    const float* __restrict__ gate, const int* __restrict__ index,
    const int* __restrict__ rank, const int* __restrict__ counts,
    const float* __restrict__ auxpart, float* __restrict__ out)
{
    const int id = threadIdx.x;          // 0..63
    const int c  = id >> 4;
    const int tp = id & 15;
    const int cnt = counts[id];

    float term = ((float)cnt * (1.0f / T_DIM)) * (auxpart[id] * (1.0f / T_DIM));

    if (cnt > 0) {
        const int g  = c * T_DIM + tp;
        const int rk = rank[g];
        if (rk < CAP) {                       // kept within capacity
            const int idx = index[g];
            const int s   = (idx == 0) ? rk : 0;
            const size_t off = ((size_t)g * E_DIM + 0) * CAP + (size_t)s;
            out[off]            = 1.0f;       // dispatch
            out[OUT_ONE + off]  = gate[g];    // combine
        }
    }

    #pragma unroll
    for (int off = 32; off; off >>= 1)
        term += __shfl_down(term, off, 64);
    if (id == 0)
        out[2 * OUT_ONE] = 16.0f * term;      // aux_loss = E * sum(density1*proxy)
}

extern "C" void kernel_launch(void* const* d_in, const int* in_sizes, int n_in,
                              void* d_out, int out_size, void* d_ws, size_t ws_size,
                              hipStream_t stream) {
    const float* in    = (const float*)d_in[0];
    const float* w     = (const float*)d_in[1];
    const float* noise = (const float*)d_in[2];
    float* out = (float*)d_out;

    char* ws = (char*)d_ws;
    float* auxpart = (float*)(ws);
    int*   counts  = (int*)(ws + 256);
    float* gate    = (float*)(ws + 512);
    int*   index   = (int*)(ws + 512 + 65536);
    int*   rank    = (int*)(ws + 512 + 131072);

    (void)hipMemsetAsync(ws, 0, 256, stream);

    fused_router_fill_kernel<<<dim3(NBLOCKS), dim3(256), 0, stream>>>(
        in, w, noise, gate, index, auxpart, (float4*)out);
    rank_kernel<<<dim3(C_DIM), dim3(256), 0, stream>>>(index, rank, counts);
    finalize_kernel<<<dim3(1), dim3(64), 0, stream>>>(gate, index, rank, counts, auxpart, out);
}

// Round 5
// 186.316 us; speedup vs baseline: 1.2425x; 1.0097x over previous
//
#include <hip/hip_runtime.h>
#include <math.h>

#define C_DIM 4
#define T_DIM 4096
#define D_DIM 1024
#define E_DIM 16
#define CAP   320
#define CT    (C_DIM * T_DIM)               // 16384 tokens
#define OUT_ONE ((size_t)CT * E_DIM * CAP)  // 83,886,080 elements per big output

#define NBLOCKS 1024                         // 16 tokens per block (4 per wave)
#define N4      ((2 * OUT_ONE) / 4)          // 41,943,040 float4 to zero
#define F4_PER_BLOCK (N4 / NBLOCKS)          // 40960 float4 per block (640KB)

// ws layout (bytes):
//   0      : auxpart f32[64]   (atomic softmax prob sums per (c,e)) - zeroed each call
//   256    : counts  i32[64]   (full per-(c,e) argmax histogram)    - zeroed each call
//   512    : gate    f32[CT]
//   66048  : index   i32[CT]

// ---------------------------------------------------------------------------
// Mega kernel: each of 1024 blocks
//   (1) routes 16 tokens (4/wave): jitter, 16 dots, softmax, argmax/gate,
//       LDS prob-sum + LDS histogram -> global atomics (fire-and-forget),
//   (2) zero-fills its contiguous 640KB slice of the two big outputs.
// The expensive full-T rank/cumsum machinery is GONE: only tokens tp<16 per
// chunk can be nonzero in the output (torch scatter semantics), their rank
// is <=16 (always within capacity) and computable from the first 16 indices.
// ---------------------------------------------------------------------------
__global__ __launch_bounds__(256) void fused_router_fill_kernel(
    const float* __restrict__ in, const float* __restrict__ w,
    const float* __restrict__ noise, float* __restrict__ gate,
    int* __restrict__ index, float* __restrict__ auxpart,
    int* __restrict__ counts, float4* __restrict__ out4)
{
    __shared__ float psum[E_DIM];
    __shared__ int   hcnt[E_DIM];
    const int tid  = threadIdx.x;
    if (tid < E_DIM) { psum[tid] = 0.0f; hcnt[tid] = 0; }
    __syncthreads();

    const int wave = tid >> 6;
    const int lane = tid & 63;
    const int g0   = blockIdx.x * 16 + wave * 4;   // 4 tokens per wave

    float acc[4][16];
    #pragma unroll
    for (int tk = 0; tk < 4; ++tk)
        #pragma unroll
        for (int e = 0; e < 16; ++e)
            acc[tk][e] = 0.0f;

    #pragma unroll
    for (int r = 0; r < 4; ++r) {
        const int d0 = r * 256 + lane * 4;
        float4 x[4];
        #pragma unroll
        for (int tk = 0; tk < 4; ++tk) {
            const float4 a = *(const float4*)(in    + (size_t)(g0 + tk) * D_DIM + d0);
            const float4 n = *(const float4*)(noise + (size_t)(g0 + tk) * D_DIM + d0);
            x[tk] = make_float4(a.x * n.x, a.y * n.y, a.z * n.z, a.w * n.w);
        }
        #pragma unroll
        for (int e = 0; e < 16; ++e) {
            const float4 wv = *(const float4*)(w + e * D_DIM + d0);
            #pragma unroll
            for (int tk = 0; tk < 4; ++tk) {
                acc[tk][e] += x[tk].x * wv.x + x[tk].y * wv.y
                            + x[tk].z * wv.z + x[tk].w * wv.w;
            }
        }
    }

    // reduce the 16 partial dots across the 64 lanes
    #pragma unroll
    for (int tk = 0; tk < 4; ++tk)
        #pragma unroll
        for (int e = 0; e < 16; ++e)
            #pragma unroll
            for (int off = 32; off; off >>= 1)
                acc[tk][e] += __shfl_down(acc[tk][e], off, 64);

    if (lane == 0) {
        #pragma unroll
        for (int tk = 0; tk < 4; ++tk) {
            const int g = g0 + tk;
            float m = -1e30f; int am = 0;
            #pragma unroll
            for (int e = 0; e < 16; ++e)
                if (acc[tk][e] > m) { m = acc[tk][e]; am = e; }
            float p[16]; float s = 0.0f;
            #pragma unroll
            for (int e = 0; e < 16; ++e) { p[e] = __expf(acc[tk][e] - m); s += p[e]; }
            const float inv = 1.0f / s;
            gate[g]  = inv;          // probs[argmax] = exp(0)/s
            index[g] = am;
            atomicAdd(&hcnt[am], 1);
            #pragma unroll
            for (int e = 0; e < 16; ++e)
                atomicAdd(&psum[e], p[e] * inv);
        }
    }
    __syncthreads();
    if (tid < 16) {
        const int c = blockIdx.x >> 8;    // 256 blocks per c
        atomicAdd(&auxpart[c * 16 + tid], psum[tid]);
        atomicAdd(&counts [c * 16 + tid], hcnt[tid]);
    }

    // ---- zero-fill this block's contiguous slice (plain stores) ----
    const float4 z = make_float4(0.f, 0.f, 0.f, 0.f);
    float4* dst = out4 + (size_t)blockIdx.x * F4_PER_BLOCK;
    #pragma unroll 4
    for (int i = tid; i < F4_PER_BLOCK; i += 256)
        dst[i] = z;
}

// ---------------------------------------------------------------------------
// Finalize: 64 lanes, lane = c*16 + tp. Nonzeros exist only at token tp<16
// (torch scatter on dim 1 with expert values as indices), e=0 slice.
// Rank of token tp within expert 0 is computed from the first 16 indices.
// ---------------------------------------------------------------------------
__global__ __launch_bounds__(64) void finalize_kernel(
    const float* __restrict__ gate, const int* __restrict__ index,
    const int* __restrict__ counts, const float* __restrict__ auxpart,
    float* __restrict__ out)
{
    const int id = threadIdx.x;          // 0..63
    const int c  = id >> 4;
    const int tp = id & 15;
    const int cnt = counts[id];

    float term = ((float)cnt * (1.0f / T_DIM)) * (auxpart[id] * (1.0f / T_DIM));

    if (cnt > 0) {                        // expert value tp appears as an argmax
        const int g    = c * T_DIM + tp;
        const int myidx = index[g];
        int s = 0;
        if (myidx == 0) {                 // rank within expert 0 among tokens 0..tp (1-based, <=16 < CAP)
            int r = 0;
            for (int t = 0; t <= tp; ++t)
                r += (index[c * T_DIM + t] == 0);
            s = r;
        }
        const size_t off = ((size_t)g * E_DIM + 0) * CAP + (size_t)s;
        out[off]            = 1.0f;       // dispatch
        out[OUT_ONE + off]  = gate[g];    // combine
    }

    #pragma unroll
    for (int off = 32; off; off >>= 1)
        term += __shfl_down(term, off, 64);
    if (id == 0)
        out[2 * OUT_ONE] = 16.0f * term;  // aux_loss = E * sum(density1*proxy)
}

extern "C" void kernel_launch(void* const* d_in, const int* in_sizes, int n_in,
                              void* d_out, int out_size, void* d_ws, size_t ws_size,
                              hipStream_t stream) {
    const float* in    = (const float*)d_in[0];
    const float* w     = (const float*)d_in[1];
    const float* noise = (const float*)d_in[2];
    float* out = (float*)d_out;

    char* ws = (char*)d_ws;
    float* auxpart = (float*)(ws);
    int*   counts  = (int*)(ws + 256);
    float* gate    = (float*)(ws + 512);
    int*   index   = (int*)(ws + 512 + 65536);

    (void)hipMemsetAsync(ws, 0, 512, stream);

    fused_router_fill_kernel<<<dim3(NBLOCKS), dim3(256), 0, stream>>>(
        in, w, noise, gate, index, auxpart, counts, (float4*)out);
    finalize_kernel<<<dim3(1), dim3(64), 0, stream>>>(gate, index, counts, auxpart, out);
}